// Round 2
// baseline (1416.330 us; speedup 1.0000x reference)
//
#include <hip/hip_runtime.h>
#include <hip/hip_bf16.h>

using bf16x8 = __attribute__((ext_vector_type(8))) short;
using f32x4  = __attribute__((ext_vector_type(4))) float;

extern "C" __device__ float __ocml_native_exp2_f32(float);

static constexpr int Bc = 4, Sc = 4096, INc = 1024, Nc = 1024, OUTc = 1024;
static constexpr int Mc = Bc * Sc;               // 16384
#define K2LE 2.8853900817779268f                 // 2 * log2(e)

__device__ __forceinline__ unsigned short f2b(float f) {
    return __builtin_bit_cast(unsigned short, __float2bfloat16(f));
}
__device__ __forceinline__ float b2f(unsigned short s) {
    unsigned int u = (unsigned int)s << 16;
    return __builtin_bit_cast(float, u);
}

// ---------------- fp32 -> (bf16 hi, bf16 lo) split, vectorized ----------------
__global__ __launch_bounds__(256) void split2(const float* __restrict__ in,
                                              unsigned short* __restrict__ hi,
                                              unsigned short* __restrict__ lo, int n4) {
    int i = blockIdx.x * blockDim.x + threadIdx.x;
    if (i >= n4) return;
    float4 v = reinterpret_cast<const float4*>(in)[i];
    ushort4 h, l;
    h.x = f2b(v.x); l.x = f2b(v.x - b2f(h.x));
    h.y = f2b(v.y); l.y = f2b(v.y - b2f(h.y));
    h.z = f2b(v.z); l.z = f2b(v.z - b2f(h.z));
    h.w = f2b(v.w); l.w = f2b(v.w - b2f(h.w));
    reinterpret_cast<ushort4*>(hi)[i] = h;
    reinterpret_cast<ushort4*>(lo)[i] = l;
}

// ---------------- transpose + split-convert: oh/ol[c][r] = split(in[r][c]) ----------------
template<bool LO>
__global__ __launch_bounds__(256) void tr_split(const float* __restrict__ in,
                                                unsigned short* __restrict__ oh,
                                                unsigned short* __restrict__ ol, int R, int C) {
    __shared__ float t[32][33];
    int c0 = blockIdx.x * 32, r0 = blockIdx.y * 32;
    for (int i = threadIdx.y; i < 32; i += 8)
        t[i][threadIdx.x] = in[(size_t)(r0 + i) * C + c0 + threadIdx.x];
    __syncthreads();
    for (int i = threadIdx.y; i < 32; i += 8) {
        float v = t[threadIdx.x][i];
        unsigned short h = f2b(v);
        size_t idx = (size_t)(c0 + i) * R + r0 + threadIdx.x;
        oh[idx] = h;
        if (LO) ol[idx] = f2b(v - b2f(h));
    }
}

// ---------------- split-precision MFMA GEMM: C = (Ah+Al)(BhT+BlT)^T, fp32 out ----------------
// C[M,N] fp32 = Ah*Bh + Ah*Bl + Al*Bh  (lo*lo dropped, ~2^-18 rel)
// Epilogue: C = K2LE * (acc + bi[col] + hs[b,col]*u[col])
__global__ __launch_bounds__(256) void gemm3_bt(const unsigned short* __restrict__ Ah,
                                                const unsigned short* __restrict__ Al,
                                                const unsigned short* __restrict__ Bh,
                                                const unsigned short* __restrict__ Bl,
                                                float* __restrict__ C, int N, int K,
                                                const float* __restrict__ bi,
                                                const float* __restrict__ u,
                                                const float* __restrict__ hs) {
    constexpr int BM = 128, BN = 128, BK = 64;
    __shared__ alignas(16) unsigned short Ash[BM * BK];
    __shared__ alignas(16) unsigned short Asl[BM * BK];
    __shared__ alignas(16) unsigned short Bsh[BN * BK];
    __shared__ alignas(16) unsigned short Bsl[BN * BK];
    const int nb = N >> 7;
    const int bm = blockIdx.x / nb, bn = blockIdx.x % nb;
    const int tid = threadIdx.x;
    const int w = tid >> 6, l = tid & 63;
    const int wr = w >> 1, wc = w & 1;
    const int r = l & 15, g4 = l >> 4;
    const int lrow = l >> 3, lcol = (l & 7) * 8;

    f32x4 acc[4][4] = {};

    const size_t aoff = (size_t)bm * BM * K;
    const size_t boff = (size_t)bn * BN * K;

    for (int k0 = 0; k0 < K; k0 += BK) {
        __syncthreads();
#pragma unroll
        for (int i = 0; i < 4; i++) {
            size_t grow = (size_t)((w * 4 + i) * 8 + lrow) * K + (k0 + lcol);
            int ldst = (w * 4 + i) * 512;
            __builtin_amdgcn_global_load_lds(
                (const __attribute__((address_space(1))) void*)(Ah + aoff + grow),
                (__attribute__((address_space(3))) void*)(Ash + ldst), 16, 0, 0);
            __builtin_amdgcn_global_load_lds(
                (const __attribute__((address_space(1))) void*)(Al + aoff + grow),
                (__attribute__((address_space(3))) void*)(Asl + ldst), 16, 0, 0);
            __builtin_amdgcn_global_load_lds(
                (const __attribute__((address_space(1))) void*)(Bh + boff + grow),
                (__attribute__((address_space(3))) void*)(Bsh + ldst), 16, 0, 0);
            __builtin_amdgcn_global_load_lds(
                (const __attribute__((address_space(1))) void*)(Bl + boff + grow),
                (__attribute__((address_space(3))) void*)(Bsl + ldst), 16, 0, 0);
        }
        __syncthreads();
#pragma unroll
        for (int kk = 0; kk < BK; kk += 32) {
            bf16x8 ah[4], al[4], bh[4], bl[4];
#pragma unroll
            for (int m = 0; m < 4; m++) {
                int off = (wr * 64 + m * 16 + r) * BK + kk + g4 * 8;
                ah[m] = *reinterpret_cast<const bf16x8*>(Ash + off);
                al[m] = *reinterpret_cast<const bf16x8*>(Asl + off);
            }
#pragma unroll
            for (int n = 0; n < 4; n++) {
                int off = (wc * 64 + n * 16 + r) * BK + kk + g4 * 8;
                bh[n] = *reinterpret_cast<const bf16x8*>(Bsh + off);
                bl[n] = *reinterpret_cast<const bf16x8*>(Bsl + off);
            }
#pragma unroll
            for (int m = 0; m < 4; m++)
#pragma unroll
                for (int n = 0; n < 4; n++) {
                    acc[m][n] = __builtin_amdgcn_mfma_f32_16x16x32_bf16(ah[m], bh[n], acc[m][n], 0, 0, 0);
                    acc[m][n] = __builtin_amdgcn_mfma_f32_16x16x32_bf16(ah[m], bl[n], acc[m][n], 0, 0, 0);
                    acc[m][n] = __builtin_amdgcn_mfma_f32_16x16x32_bf16(al[m], bh[n], acc[m][n], 0, 0, 0);
                }
        }
    }

    const int bbase = ((bm * BM) / Sc) * Nc;     // batch uniform per block (BM divides Sc)
#pragma unroll
    for (int m = 0; m < 4; m++) {
        int row = bm * BM + wr * 64 + m * 16 + g4 * 4;
#pragma unroll
        for (int n = 0; n < 4; n++) {
            int col = bn * BN + wc * 64 + n * 16 + r;
            float extra = bi[col] + hs[bbase + col] * u[col];
#pragma unroll
            for (int q = 0; q < 4; q++)
                C[(size_t)(row + q) * N + col] = (acc[m][n][q] + extra) * K2LE;
        }
    }
}

// ---------------- plain bf16 MFMA GEMM: C[M,N] fp32 = A[M,K] * BT[N,K]^T ----------------
__global__ __launch_bounds__(256) void gemm_bt(const unsigned short* __restrict__ A,
                                               const unsigned short* __restrict__ BT,
                                               float* __restrict__ C, int N, int K) {
    constexpr int BM = 128, BN = 128, BK = 64;
    __shared__ alignas(16) unsigned short As[BM * BK];
    __shared__ alignas(16) unsigned short Bs[BN * BK];
    const int nb = N >> 7;
    const int bm = blockIdx.x / nb, bn = blockIdx.x % nb;
    const int tid = threadIdx.x;
    const int w = tid >> 6, l = tid & 63;
    const int wr = w >> 1, wc = w & 1;
    const int r = l & 15, g4 = l >> 4;
    const int lrow = l >> 3, lcol = (l & 7) * 8;

    f32x4 acc[4][4] = {};

    const unsigned short* Ab = A + (size_t)bm * BM * K;
    const unsigned short* Bb = BT + (size_t)bn * BN * K;

    for (int k0 = 0; k0 < K; k0 += BK) {
        __syncthreads();
#pragma unroll
        for (int i = 0; i < 4; i++) {
            const unsigned short* g = Ab + (size_t)((w * 4 + i) * 8 + lrow) * K + (k0 + lcol);
            __builtin_amdgcn_global_load_lds(
                (const __attribute__((address_space(1))) void*)g,
                (__attribute__((address_space(3))) void*)(As + (w * 4 + i) * 512), 16, 0, 0);
        }
#pragma unroll
        for (int i = 0; i < 4; i++) {
            const unsigned short* g = Bb + (size_t)((w * 4 + i) * 8 + lrow) * K + (k0 + lcol);
            __builtin_amdgcn_global_load_lds(
                (const __attribute__((address_space(1))) void*)g,
                (__attribute__((address_space(3))) void*)(Bs + (w * 4 + i) * 512), 16, 0, 0);
        }
        __syncthreads();
#pragma unroll
        for (int kk = 0; kk < BK; kk += 32) {
            bf16x8 af[4], bfr[4];
#pragma unroll
            for (int m = 0; m < 4; m++)
                af[m] = *reinterpret_cast<const bf16x8*>(As + (wr * 64 + m * 16 + r) * BK + kk + g4 * 8);
#pragma unroll
            for (int n = 0; n < 4; n++)
                bfr[n] = *reinterpret_cast<const bf16x8*>(Bs + (wc * 64 + n * 16 + r) * BK + kk + g4 * 8);
#pragma unroll
            for (int m = 0; m < 4; m++)
#pragma unroll
                for (int n = 0; n < 4; n++)
                    acc[m][n] = __builtin_amdgcn_mfma_f32_16x16x32_bf16(af[m], bfr[n], acc[m][n], 0, 0, 0);
        }
    }

#pragma unroll
    for (int m = 0; m < 4; m++) {
        int row = bm * BM + wr * 64 + m * 16 + g4 * 4;
#pragma unroll
        for (int n = 0; n < 4; n++) {
            int col = bn * BN + wc * 64 + n * 16 + r;
#pragma unroll
            for (int q = 0; q < 4; q++)
                C[(size_t)(row + q) * N + col] = acc[m][n][q];
        }
    }
}

// ---------------- sequential tanh recurrence ----------------
// xp holds K2LE*(x@Wi + bi + hippo). h = tanh(z) = 1 - 2/(exp2(K2LE*z)+1).
// Critical path per step: fma -> v_exp -> add -> v_rcp. Deep (32) register prefetch.
__global__ __launch_bounds__(64) void scan2(const float* __restrict__ xp,
                                            const float* __restrict__ w,
                                            const float* __restrict__ h0,
                                            unsigned short* __restrict__ states,
                                            float* __restrict__ out_state) {
    int tid = blockIdx.x * 64 + threadIdx.x;           // 0..4095 = b*1024+n
    int n = tid & (Nc - 1);
    int b = tid >> 10;
    float ww = w[n] * K2LE;
    float nw2 = -2.f * ww;
    float rr = 0.5f - 0.5f * h0[tid];                  // h = 1 - 2r
    const float* xrow = xp + ((size_t)b << 22) + n;    // b*S*N
    unsigned short* srow = states + ((size_t)b << 22) + n;

    constexpr int D = 32;
    float xv[D];
#pragma unroll
    for (int d = 0; d < D; d++) xv[d] = xrow[(size_t)d << 10];

    for (int t0 = 0; t0 < Sc; t0 += D) {
#pragma unroll
        for (int d = 0; d < D; d++) {
            int t = t0 + d;
            float c = ww + xv[d];                       // off critical path
            if (t + D < Sc) xv[d] = xrow[(size_t)(t + D) << 10];   // deep prefetch
            float z = fmaf(nw2, rr, c);                 // = K2LE*(h*w + x + bias)
            float e = __ocml_native_exp2_f32(z);        // v_exp_f32
            rr = __builtin_amdgcn_rcpf(e + 1.f);        // v_rcp_f32
            srow[(size_t)t << 10] = f2b(fmaf(-2.f, rr, 1.f));
        }
    }
    out_state[tid] = fmaf(-2.f, rr, 1.f);
}

extern "C" void kernel_launch(void* const* d_in, const int* in_sizes, int n_in,
                              void* d_out, int out_size, void* d_ws, size_t ws_size,
                              hipStream_t stream) {
    const float* x  = (const float*)d_in[0];
    const float* Wi = (const float*)d_in[1];
    const float* bi = (const float*)d_in[2];
    const float* w  = (const float*)d_in[3];
    const float* u  = (const float*)d_in[4];
    const float* Wo = (const float*)d_in[5];
    const float* h0 = (const float*)d_in[6];
    const float* hs = (const float*)d_in[7];
    float* out = (float*)d_out;                          // [M, OUT] fp32
    float* out_state = out + (size_t)Mc * OUTc;          // [B, N] fp32
    float* xp = out;                                     // xp scratch lives in d_out (dead before GEMM2)

    // ws layout (70 MiB): xh 32M | xl 32M | WiTh 2M | WiTl 2M | WoT 2M ; states reuse xh
    char* ws = (char*)d_ws;
    unsigned short* xh   = (unsigned short*)ws;
    unsigned short* xl   = (unsigned short*)(ws + 33554432);
    unsigned short* WiTh = (unsigned short*)(ws + 67108864);
    unsigned short* WiTl = (unsigned short*)(ws + 69206016);
    unsigned short* WoT  = (unsigned short*)(ws + 71303168);
    unsigned short* states = xh;                         // xh dead after gemm3

    split2<<<(Mc * INc / 4 + 255) / 256, 256, 0, stream>>>(x, xh, xl, Mc * INc / 4);
    dim3 tb(32, 8);
    tr_split<true ><<<dim3(Nc / 32, INc / 32), tb, 0, stream>>>(Wi, WiTh, WiTl, INc, Nc);
    tr_split<false><<<dim3(OUTc / 32, Nc / 32), tb, 0, stream>>>(Wo, WoT, nullptr, Nc, OUTc);

    gemm3_bt<<<(Mc / 128) * (Nc / 128), 256, 0, stream>>>(xh, xl, WiTh, WiTl, xp, Nc, INc, bi, u, hs);
    scan2<<<64, 64, 0, stream>>>(xp, w, h0, states, out_state);
    gemm_bt<<<(Mc / 128) * (OUTc / 128), 256, 0, stream>>>(states, WoT, out, OUTc, Nc);
}

// Round 3
// 334.652 us; speedup vs baseline: 4.2322x; 4.2322x over previous
//
#include <hip/hip_runtime.h>
#include <hip/hip_bf16.h>

using bf16x8 = __attribute__((ext_vector_type(8))) short;
using f32x4  = __attribute__((ext_vector_type(4))) float;

extern "C" __device__ float __ocml_native_exp2_f32(float);

static constexpr int Bc = 4, Sc = 4096, INc = 1024, Nc = 1024, OUTc = 1024;
static constexpr int Mc = Bc * Sc;               // 16384
#define K2LE 2.8853900817779268f                 // 2 * log2(e)

__device__ __forceinline__ unsigned short f2b(float f) {
    return __builtin_bit_cast(unsigned short, __float2bfloat16(f));
}
__device__ __forceinline__ float b2f(unsigned short s) {
    unsigned int u = (unsigned int)s << 16;
    return __builtin_bit_cast(float, u);
}

// ---------------- fp32 -> (bf16 hi, bf16 lo) split, vectorized ----------------
__global__ __launch_bounds__(256) void split2(const float* __restrict__ in,
                                              unsigned short* __restrict__ hi,
                                              unsigned short* __restrict__ lo, int n4) {
    int i = blockIdx.x * blockDim.x + threadIdx.x;
    if (i >= n4) return;
    float4 v = reinterpret_cast<const float4*>(in)[i];
    ushort4 h, l;
    h.x = f2b(v.x); l.x = f2b(v.x - b2f(h.x));
    h.y = f2b(v.y); l.y = f2b(v.y - b2f(h.y));
    h.z = f2b(v.z); l.z = f2b(v.z - b2f(h.z));
    h.w = f2b(v.w); l.w = f2b(v.w - b2f(h.w));
    reinterpret_cast<ushort4*>(hi)[i] = h;
    reinterpret_cast<ushort4*>(lo)[i] = l;
}

// ---------------- transpose + split-convert: oh/ol[c][r] = split(in[r][c]) ----------------
template<bool LO>
__global__ __launch_bounds__(256) void tr_split(const float* __restrict__ in,
                                                unsigned short* __restrict__ oh,
                                                unsigned short* __restrict__ ol, int R, int C) {
    __shared__ float t[32][33];
    int c0 = blockIdx.x * 32, r0 = blockIdx.y * 32;
    for (int i = threadIdx.y; i < 32; i += 8)
        t[i][threadIdx.x] = in[(size_t)(r0 + i) * C + c0 + threadIdx.x];
    __syncthreads();
    for (int i = threadIdx.y; i < 32; i += 8) {
        float v = t[threadIdx.x][i];
        unsigned short h = f2b(v);
        size_t idx = (size_t)(c0 + i) * R + r0 + threadIdx.x;
        oh[idx] = h;
        if (LO) ol[idx] = f2b(v - b2f(h));
    }
}

// ---------------- split-precision MFMA GEMM: C = (Ah+Al)(BhT+BlT)^T, fp32 out ----------------
// C[M,N] fp32 = Ah*Bh + Ah*Bl + Al*Bh  (lo*lo dropped, ~2^-18 rel)
// Epilogue: C = K2LE * (acc + bi[col] + hs[b,col]*u[col])
__global__ __launch_bounds__(256) void gemm3_bt(const unsigned short* __restrict__ Ah,
                                                const unsigned short* __restrict__ Al,
                                                const unsigned short* __restrict__ Bh,
                                                const unsigned short* __restrict__ Bl,
                                                float* __restrict__ C, int N, int K,
                                                const float* __restrict__ bi,
                                                const float* __restrict__ u,
                                                const float* __restrict__ hs) {
    constexpr int BM = 128, BN = 128, BK = 64;
    __shared__ alignas(16) unsigned short Ash[BM * BK];
    __shared__ alignas(16) unsigned short Asl[BM * BK];
    __shared__ alignas(16) unsigned short Bsh[BN * BK];
    __shared__ alignas(16) unsigned short Bsl[BN * BK];
    const int nb = N >> 7;
    const int bm = blockIdx.x / nb, bn = blockIdx.x % nb;
    const int tid = threadIdx.x;
    const int w = tid >> 6, l = tid & 63;
    const int wr = w >> 1, wc = w & 1;
    const int r = l & 15, g4 = l >> 4;
    const int lrow = l >> 3, lcol = (l & 7) * 8;

    f32x4 acc[4][4] = {};

    const size_t aoff = (size_t)bm * BM * K;
    const size_t boff = (size_t)bn * BN * K;

    for (int k0 = 0; k0 < K; k0 += BK) {
        __syncthreads();
#pragma unroll
        for (int i = 0; i < 4; i++) {
            size_t grow = (size_t)((w * 4 + i) * 8 + lrow) * K + (k0 + lcol);
            int ldst = (w * 4 + i) * 512;
            __builtin_amdgcn_global_load_lds(
                (const __attribute__((address_space(1))) void*)(Ah + aoff + grow),
                (__attribute__((address_space(3))) void*)(Ash + ldst), 16, 0, 0);
            __builtin_amdgcn_global_load_lds(
                (const __attribute__((address_space(1))) void*)(Al + aoff + grow),
                (__attribute__((address_space(3))) void*)(Asl + ldst), 16, 0, 0);
            __builtin_amdgcn_global_load_lds(
                (const __attribute__((address_space(1))) void*)(Bh + boff + grow),
                (__attribute__((address_space(3))) void*)(Bsh + ldst), 16, 0, 0);
            __builtin_amdgcn_global_load_lds(
                (const __attribute__((address_space(1))) void*)(Bl + boff + grow),
                (__attribute__((address_space(3))) void*)(Bsl + ldst), 16, 0, 0);
        }
        __syncthreads();
#pragma unroll
        for (int kk = 0; kk < BK; kk += 32) {
            bf16x8 ah[4], al[4], bh[4], bl[4];
#pragma unroll
            for (int m = 0; m < 4; m++) {
                int off = (wr * 64 + m * 16 + r) * BK + kk + g4 * 8;
                ah[m] = *reinterpret_cast<const bf16x8*>(Ash + off);
                al[m] = *reinterpret_cast<const bf16x8*>(Asl + off);
            }
#pragma unroll
            for (int n = 0; n < 4; n++) {
                int off = (wc * 64 + n * 16 + r) * BK + kk + g4 * 8;
                bh[n] = *reinterpret_cast<const bf16x8*>(Bsh + off);
                bl[n] = *reinterpret_cast<const bf16x8*>(Bsl + off);
            }
#pragma unroll
            for (int m = 0; m < 4; m++)
#pragma unroll
                for (int n = 0; n < 4; n++) {
                    acc[m][n] = __builtin_amdgcn_mfma_f32_16x16x32_bf16(ah[m], bh[n], acc[m][n], 0, 0, 0);
                    acc[m][n] = __builtin_amdgcn_mfma_f32_16x16x32_bf16(ah[m], bl[n], acc[m][n], 0, 0, 0);
                    acc[m][n] = __builtin_amdgcn_mfma_f32_16x16x32_bf16(al[m], bh[n], acc[m][n], 0, 0, 0);
                }
        }
    }

    const int bbase = ((bm * BM) / Sc) * Nc;     // batch uniform per block (BM divides Sc)
#pragma unroll
    for (int m = 0; m < 4; m++) {
        int row = bm * BM + wr * 64 + m * 16 + g4 * 4;
#pragma unroll
        for (int n = 0; n < 4; n++) {
            int col = bn * BN + wc * 64 + n * 16 + r;
            float extra = bi[col] + hs[bbase + col] * u[col];
#pragma unroll
            for (int q = 0; q < 4; q++)
                C[(size_t)(row + q) * N + col] = (acc[m][n][q] + extra) * K2LE;
        }
    }
}

// ---------------- plain bf16 MFMA GEMM: C[M,N] fp32 = A[M,K] * BT[N,K]^T ----------------
__global__ __launch_bounds__(256) void gemm_bt(const unsigned short* __restrict__ A,
                                               const unsigned short* __restrict__ BT,
                                               float* __restrict__ C, int N, int K) {
    constexpr int BM = 128, BN = 128, BK = 64;
    __shared__ alignas(16) unsigned short As[BM * BK];
    __shared__ alignas(16) unsigned short Bs[BN * BK];
    const int nb = N >> 7;
    const int bm = blockIdx.x / nb, bn = blockIdx.x % nb;
    const int tid = threadIdx.x;
    const int w = tid >> 6, l = tid & 63;
    const int wr = w >> 1, wc = w & 1;
    const int r = l & 15, g4 = l >> 4;
    const int lrow = l >> 3, lcol = (l & 7) * 8;

    f32x4 acc[4][4] = {};

    const unsigned short* Ab = A + (size_t)bm * BM * K;
    const unsigned short* Bb = BT + (size_t)bn * BN * K;

    for (int k0 = 0; k0 < K; k0 += BK) {
        __syncthreads();
#pragma unroll
        for (int i = 0; i < 4; i++) {
            const unsigned short* g = Ab + (size_t)((w * 4 + i) * 8 + lrow) * K + (k0 + lcol);
            __builtin_amdgcn_global_load_lds(
                (const __attribute__((address_space(1))) void*)g,
                (__attribute__((address_space(3))) void*)(As + (w * 4 + i) * 512), 16, 0, 0);
        }
#pragma unroll
        for (int i = 0; i < 4; i++) {
            const unsigned short* g = Bb + (size_t)((w * 4 + i) * 8 + lrow) * K + (k0 + lcol);
            __builtin_amdgcn_global_load_lds(
                (const __attribute__((address_space(1))) void*)g,
                (__attribute__((address_space(3))) void*)(Bs + (w * 4 + i) * 512), 16, 0, 0);
        }
        __syncthreads();
#pragma unroll
        for (int kk = 0; kk < BK; kk += 32) {
            bf16x8 af[4], bfr[4];
#pragma unroll
            for (int m = 0; m < 4; m++)
                af[m] = *reinterpret_cast<const bf16x8*>(As + (wr * 64 + m * 16 + r) * BK + kk + g4 * 8);
#pragma unroll
            for (int n = 0; n < 4; n++)
                bfr[n] = *reinterpret_cast<const bf16x8*>(Bs + (wc * 64 + n * 16 + r) * BK + kk + g4 * 8);
#pragma unroll
            for (int m = 0; m < 4; m++)
#pragma unroll
                for (int n = 0; n < 4; n++)
                    acc[m][n] = __builtin_amdgcn_mfma_f32_16x16x32_bf16(af[m], bfr[n], acc[m][n], 0, 0, 0);
        }
    }

#pragma unroll
    for (int m = 0; m < 4; m++) {
        int row = bm * BM + wr * 64 + m * 16 + g4 * 4;
#pragma unroll
        for (int n = 0; n < 4; n++) {
            int col = bn * BN + wc * 64 + n * 16 + r;
#pragma unroll
            for (int q = 0; q < 4; q++)
                C[(size_t)(row + q) * N + col] = acc[m][n][q];
        }
    }
}

// ---------------- sequential tanh recurrence, LDS-batched stores ----------------
// xp holds K2LE*(x@Wi + bi + hippo). h = tanh(z) = 1 - 2/(exp2(z')+1), z' pre-scaled.
// Per step: fma -> v_exp -> add -> v_rcp on the rr chain; h -> ds_write_b16 (lgkm, off
// the VMEM queue). Every 32 steps: LDS transpose-flush as 4x ds_read_b128 +
// 4x coalesced global_store_dwordx4. Prefetch: 2-block double buffer (xa/xb).
struct ScanCtx {
    const float* xrow;
    unsigned short* srow;   // states + b*S*N
    unsigned short* hb;     // LDS, row stride 72 shorts (144 B)
    int l, n0;
    float ww, nw2;
};

template<bool PREF>
__device__ __forceinline__ void scan_block32(ScanCtx& cx, float (&buf)[32],
                                             int tblk, float& rr) {
#pragma unroll
    for (int d = 0; d < 32; d++) {
        float c = cx.ww + buf[d];                        // off critical path
        if (PREF) buf[d] = cx.xrow[(size_t)(tblk + 64 + d) << 10];   // 2 blocks ahead
        float z = fmaf(cx.nw2, rr, c);
        float e = __ocml_native_exp2_f32(z);             // v_exp_f32
        rr = __builtin_amdgcn_rcpf(e + 1.f);             // v_rcp_f32
        cx.hb[d * 72 + cx.l] = f2b(fmaf(-2.f, rr, 1.f)); // LDS, 2-way alias = free
    }
    __syncthreads();
    {
        int row = cx.l & 31, half = cx.l >> 5;
#pragma unroll
        for (int i = 0; i < 4; i++) {
            int chunk = half + 2 * i;                    // 0..7
            uint4 v = *reinterpret_cast<const uint4*>(&cx.hb[row * 72 + chunk * 8]);
            *reinterpret_cast<uint4*>(&cx.srow[((size_t)(tblk + row) << 10) + cx.n0 + chunk * 8]) = v;
        }
    }
    __syncthreads();
}

__global__ __launch_bounds__(64) void scan3(const float* __restrict__ xp,
                                            const float* __restrict__ w,
                                            const float* __restrict__ h0,
                                            unsigned short* __restrict__ states,
                                            float* __restrict__ out_state) {
    __shared__ alignas(16) unsigned short hb[32 * 72];   // 4.5 KiB
    const int l = threadIdx.x;
    const int tid = blockIdx.x * 64 + l;                 // b*1024 + n
    const int n = tid & (Nc - 1);
    const int b = tid >> 10;
    ScanCtx cx;
    cx.l = l;
    cx.n0 = (blockIdx.x & 15) * 64;                      // 16 blocks per batch
    cx.ww = w[n] * K2LE;
    cx.nw2 = -2.f * cx.ww;
    cx.xrow = xp + ((size_t)b << 22) + n;
    cx.srow = states + ((size_t)b << 22);
    cx.hb = hb;
    float rr = 0.5f - 0.5f * h0[tid];                    // h = 1 - 2*rr

    float xa[32], xb[32];
#pragma unroll
    for (int d = 0; d < 32; d++) xa[d] = cx.xrow[(size_t)d << 10];
#pragma unroll
    for (int d = 0; d < 32; d++) xb[d] = cx.xrow[(size_t)(32 + d) << 10];

    int t0 = 0;
    for (; t0 + 64 < Sc; t0 += 64) {
        scan_block32<true>(cx, xa, t0, rr);
        scan_block32<true>(cx, xb, t0 + 32, rr);
    }
    scan_block32<false>(cx, xa, t0, rr);
    scan_block32<false>(cx, xb, t0 + 32, rr);

    out_state[tid] = fmaf(-2.f, rr, 1.f);
}

extern "C" void kernel_launch(void* const* d_in, const int* in_sizes, int n_in,
                              void* d_out, int out_size, void* d_ws, size_t ws_size,
                              hipStream_t stream) {
    const float* x  = (const float*)d_in[0];
    const float* Wi = (const float*)d_in[1];
    const float* bi = (const float*)d_in[2];
    const float* w  = (const float*)d_in[3];
    const float* u  = (const float*)d_in[4];
    const float* Wo = (const float*)d_in[5];
    const float* h0 = (const float*)d_in[6];
    const float* hs = (const float*)d_in[7];
    float* out = (float*)d_out;                          // [M, OUT] fp32
    float* out_state = out + (size_t)Mc * OUTc;          // [B, N] fp32
    float* xp = out;                                     // xp scratch lives in d_out (dead before GEMM2)

    // ws layout (70 MiB): xh 32M | xl 32M | WiTh 2M | WiTl 2M | WoT 2M ; states reuse xh
    char* ws = (char*)d_ws;
    unsigned short* xh   = (unsigned short*)ws;
    unsigned short* xl   = (unsigned short*)(ws + 33554432);
    unsigned short* WiTh = (unsigned short*)(ws + 67108864);
    unsigned short* WiTl = (unsigned short*)(ws + 69206016);
    unsigned short* WoT  = (unsigned short*)(ws + 71303168);
    unsigned short* states = xh;                         // xh dead after gemm3

    split2<<<(Mc * INc / 4 + 255) / 256, 256, 0, stream>>>(x, xh, xl, Mc * INc / 4);
    dim3 tb(32, 8);
    tr_split<true ><<<dim3(Nc / 32, INc / 32), tb, 0, stream>>>(Wi, WiTh, WiTl, INc, Nc);
    tr_split<false><<<dim3(OUTc / 32, Nc / 32), tb, 0, stream>>>(Wo, WoT, nullptr, Nc, OUTc);

    gemm3_bt<<<(Mc / 128) * (Nc / 128), 256, 0, stream>>>(xh, xl, WiTh, WiTl, xp, Nc, INc, bi, u, hs);
    scan3<<<64, 64, 0, stream>>>(xp, w, h0, states, out_state);
    gemm_bt<<<(Mc / 128) * (OUTc / 128), 256, 0, stream>>>(states, WoT, out, OUTc, Nc);
}

// Round 4
// 290.040 us; speedup vs baseline: 4.8832x; 1.1538x over previous
//
#include <hip/hip_runtime.h>
#include <hip/hip_bf16.h>

using bf16x8 = __attribute__((ext_vector_type(8))) short;
using f32x4  = __attribute__((ext_vector_type(4))) float;

extern "C" __device__ float __ocml_native_exp2_f32(float);

static constexpr int Bc = 4, Sc = 4096, INc = 1024, Nc = 1024, OUTc = 1024;
static constexpr int Mc = Bc * Sc;               // 16384
#define K2LE 2.8853900817779268f                 // 2 * log2(e)

__device__ __forceinline__ unsigned short f2b(float f) {
    return __builtin_bit_cast(unsigned short, __float2bfloat16(f));
}
__device__ __forceinline__ float b2f(unsigned short s) {
    unsigned int u = (unsigned int)s << 16;
    return __builtin_bit_cast(float, u);
}

// ---------------- fp32 -> (bf16 hi, bf16 lo) split, vectorized ----------------
__global__ __launch_bounds__(256) void split2(const float* __restrict__ in,
                                              unsigned short* __restrict__ hi,
                                              unsigned short* __restrict__ lo, int n4) {
    int i = blockIdx.x * blockDim.x + threadIdx.x;
    if (i >= n4) return;
    float4 v = reinterpret_cast<const float4*>(in)[i];
    ushort4 h, l;
    h.x = f2b(v.x); l.x = f2b(v.x - b2f(h.x));
    h.y = f2b(v.y); l.y = f2b(v.y - b2f(h.y));
    h.z = f2b(v.z); l.z = f2b(v.z - b2f(h.z));
    h.w = f2b(v.w); l.w = f2b(v.w - b2f(h.w));
    reinterpret_cast<ushort4*>(hi)[i] = h;
    reinterpret_cast<ushort4*>(lo)[i] = l;
}

// ---------------- transpose + split-convert: oh/ol[c][r] = split(in[r][c]) ----------------
template<bool LO>
__global__ __launch_bounds__(256) void tr_split(const float* __restrict__ in,
                                                unsigned short* __restrict__ oh,
                                                unsigned short* __restrict__ ol, int R, int C) {
    __shared__ float t[32][33];
    int c0 = blockIdx.x * 32, r0 = blockIdx.y * 32;
    for (int i = threadIdx.y; i < 32; i += 8)
        t[i][threadIdx.x] = in[(size_t)(r0 + i) * C + c0 + threadIdx.x];
    __syncthreads();
    for (int i = threadIdx.y; i < 32; i += 8) {
        float v = t[threadIdx.x][i];
        unsigned short h = f2b(v);
        size_t idx = (size_t)(c0 + i) * R + r0 + threadIdx.x;
        oh[idx] = h;
        if (LO) ol[idx] = f2b(v - b2f(h));
    }
}

// ---------------- split-precision MFMA GEMM: C = (Ah+Al)(BhT+BlT)^T, fp32 out ----------------
// C[M,N] fp32 = Ah*Bh + Ah*Bl + Al*Bh  (lo*lo dropped, ~2^-18 rel)
// Epilogue: C = K2LE * (acc + bi[col] + hs[b,col]*u[col] + w[col])   <- w folded for scan
__global__ __launch_bounds__(256) void gemm3_bt(const unsigned short* __restrict__ Ah,
                                                const unsigned short* __restrict__ Al,
                                                const unsigned short* __restrict__ Bh,
                                                const unsigned short* __restrict__ Bl,
                                                float* __restrict__ C, int N, int K,
                                                const float* __restrict__ bi,
                                                const float* __restrict__ u,
                                                const float* __restrict__ hs,
                                                const float* __restrict__ wv) {
    constexpr int BM = 128, BN = 128, BK = 64;
    __shared__ alignas(16) unsigned short Ash[BM * BK];
    __shared__ alignas(16) unsigned short Asl[BM * BK];
    __shared__ alignas(16) unsigned short Bsh[BN * BK];
    __shared__ alignas(16) unsigned short Bsl[BN * BK];
    const int nb = N >> 7;
    const int bm = blockIdx.x / nb, bn = blockIdx.x % nb;
    const int tid = threadIdx.x;
    const int w = tid >> 6, l = tid & 63;
    const int wr = w >> 1, wc = w & 1;
    const int r = l & 15, g4 = l >> 4;
    const int lrow = l >> 3, lcol = (l & 7) * 8;

    f32x4 acc[4][4] = {};

    const size_t aoff = (size_t)bm * BM * K;
    const size_t boff = (size_t)bn * BN * K;

    for (int k0 = 0; k0 < K; k0 += BK) {
        __syncthreads();
#pragma unroll
        for (int i = 0; i < 4; i++) {
            size_t grow = (size_t)((w * 4 + i) * 8 + lrow) * K + (k0 + lcol);
            int ldst = (w * 4 + i) * 512;
            __builtin_amdgcn_global_load_lds(
                (const __attribute__((address_space(1))) void*)(Ah + aoff + grow),
                (__attribute__((address_space(3))) void*)(Ash + ldst), 16, 0, 0);
            __builtin_amdgcn_global_load_lds(
                (const __attribute__((address_space(1))) void*)(Al + aoff + grow),
                (__attribute__((address_space(3))) void*)(Asl + ldst), 16, 0, 0);
            __builtin_amdgcn_global_load_lds(
                (const __attribute__((address_space(1))) void*)(Bh + boff + grow),
                (__attribute__((address_space(3))) void*)(Bsh + ldst), 16, 0, 0);
            __builtin_amdgcn_global_load_lds(
                (const __attribute__((address_space(1))) void*)(Bl + boff + grow),
                (__attribute__((address_space(3))) void*)(Bsl + ldst), 16, 0, 0);
        }
        __syncthreads();
#pragma unroll
        for (int kk = 0; kk < BK; kk += 32) {
            bf16x8 ah[4], al[4], bh[4], bl[4];
#pragma unroll
            for (int m = 0; m < 4; m++) {
                int off = (wr * 64 + m * 16 + r) * BK + kk + g4 * 8;
                ah[m] = *reinterpret_cast<const bf16x8*>(Ash + off);
                al[m] = *reinterpret_cast<const bf16x8*>(Asl + off);
            }
#pragma unroll
            for (int n = 0; n < 4; n++) {
                int off = (wc * 64 + n * 16 + r) * BK + kk + g4 * 8;
                bh[n] = *reinterpret_cast<const bf16x8*>(Bsh + off);
                bl[n] = *reinterpret_cast<const bf16x8*>(Bsl + off);
            }
#pragma unroll
            for (int m = 0; m < 4; m++)
#pragma unroll
                for (int n = 0; n < 4; n++) {
                    acc[m][n] = __builtin_amdgcn_mfma_f32_16x16x32_bf16(ah[m], bh[n], acc[m][n], 0, 0, 0);
                    acc[m][n] = __builtin_amdgcn_mfma_f32_16x16x32_bf16(ah[m], bl[n], acc[m][n], 0, 0, 0);
                    acc[m][n] = __builtin_amdgcn_mfma_f32_16x16x32_bf16(al[m], bh[n], acc[m][n], 0, 0, 0);
                }
        }
    }

    const int bbase = ((bm * BM) / Sc) * Nc;     // batch uniform per block (BM divides Sc)
#pragma unroll
    for (int m = 0; m < 4; m++) {
        int row = bm * BM + wr * 64 + m * 16 + g4 * 4;
#pragma unroll
        for (int n = 0; n < 4; n++) {
            int col = bn * BN + wc * 64 + n * 16 + r;
            float extra = bi[col] + hs[bbase + col] * u[col] + wv[col];
#pragma unroll
            for (int q = 0; q < 4; q++)
                C[(size_t)(row + q) * N + col] = (acc[m][n][q] + extra) * K2LE;
        }
    }
}

// ---------------- plain bf16 MFMA GEMM: C[M,N] fp32 = A[M,K] * BT[N,K]^T ----------------
__global__ __launch_bounds__(256) void gemm_bt(const unsigned short* __restrict__ A,
                                               const unsigned short* __restrict__ BT,
                                               float* __restrict__ C, int N, int K) {
    constexpr int BM = 128, BN = 128, BK = 64;
    __shared__ alignas(16) unsigned short As[BM * BK];
    __shared__ alignas(16) unsigned short Bs[BN * BK];
    const int nb = N >> 7;
    const int bm = blockIdx.x / nb, bn = blockIdx.x % nb;
    const int tid = threadIdx.x;
    const int w = tid >> 6, l = tid & 63;
    const int wr = w >> 1, wc = w & 1;
    const int r = l & 15, g4 = l >> 4;
    const int lrow = l >> 3, lcol = (l & 7) * 8;

    f32x4 acc[4][4] = {};

    const unsigned short* Ab = A + (size_t)bm * BM * K;
    const unsigned short* Bb = BT + (size_t)bn * BN * K;

    for (int k0 = 0; k0 < K; k0 += BK) {
        __syncthreads();
#pragma unroll
        for (int i = 0; i < 4; i++) {
            const unsigned short* g = Ab + (size_t)((w * 4 + i) * 8 + lrow) * K + (k0 + lcol);
            __builtin_amdgcn_global_load_lds(
                (const __attribute__((address_space(1))) void*)g,
                (__attribute__((address_space(3))) void*)(As + (w * 4 + i) * 512), 16, 0, 0);
        }
#pragma unroll
        for (int i = 0; i < 4; i++) {
            const unsigned short* g = Bb + (size_t)((w * 4 + i) * 8 + lrow) * K + (k0 + lcol);
            __builtin_amdgcn_global_load_lds(
                (const __attribute__((address_space(1))) void*)g,
                (__attribute__((address_space(3))) void*)(Bs + (w * 4 + i) * 512), 16, 0, 0);
        }
        __syncthreads();
#pragma unroll
        for (int kk = 0; kk < BK; kk += 32) {
            bf16x8 af[4], bfr[4];
#pragma unroll
            for (int m = 0; m < 4; m++)
                af[m] = *reinterpret_cast<const bf16x8*>(As + (wr * 64 + m * 16 + r) * BK + kk + g4 * 8);
#pragma unroll
            for (int n = 0; n < 4; n++)
                bfr[n] = *reinterpret_cast<const bf16x8*>(Bs + (wc * 64 + n * 16 + r) * BK + kk + g4 * 8);
#pragma unroll
            for (int m = 0; m < 4; m++)
#pragma unroll
                for (int n = 0; n < 4; n++)
                    acc[m][n] = __builtin_amdgcn_mfma_f32_16x16x32_bf16(af[m], bfr[n], acc[m][n], 0, 0, 0);
        }
    }

#pragma unroll
    for (int m = 0; m < 4; m++) {
        int row = bm * BM + wr * 64 + m * 16 + g4 * 4;
#pragma unroll
        for (int n = 0; n < 4; n++) {
            int col = bn * BN + wc * 64 + n * 16 + r;
#pragma unroll
            for (int q = 0; q < 4; q++)
                C[(size_t)(row + q) * N + col] = acc[m][n][q];
        }
    }
}

// ---------------- sequential tanh recurrence: producer-consumer waves ----------------
// xp holds K2LE*(x@Wi + bi + hippo + w). Wave 0 (producer): per step
// z = fma(nw2, rr, x); e = exp2(z); rr = rcp(e+1); ds_write_b32 rr.  That's it.
// Wave 1 (consumer): per 32-step chunk, reads rr from LDS, h = 1-2rr, packs bf16,
// coalesced dwordx4 stores. Double-buffered LDS; raw s_barrier + lgkmcnt-only
// fence on wave 0 so the x-prefetch VMEM queue is NEVER drained.
static constexpr int SROW = 68;   // floats per LDS row (64 + 4 pad, 16B-aligned)

template<bool PREF>
__device__ __forceinline__ void sblk(const float* __restrict__ xrow,
                                     float (&cur)[32], float (&nxt)[32],
                                     float* __restrict__ hbl, int tblk, float nw2, float& rr) {
#pragma unroll
    for (int d = 0; d < 32; d++) {
        if (PREF) nxt[d] = xrow[(size_t)(tblk + 32 + d) << 10];   // 1 chunk ahead
        float z = fmaf(nw2, rr, cur[d]);
        float e = __ocml_native_exp2_f32(z);          // v_exp_f32
        rr = __builtin_amdgcn_rcpf(e + 1.f);          // v_rcp_f32
        hbl[d * SROW] = rr;                            // ds_write_b32, imm offset
    }
    asm volatile("s_waitcnt lgkmcnt(0)" ::: "memory");
    __builtin_amdgcn_s_barrier();
}

__device__ __forceinline__ unsigned int pk2(float a, float b) {
    return ((unsigned int)f2b(fmaf(-2.f, b, 1.f)) << 16) | f2b(fmaf(-2.f, a, 1.f));
}

__device__ __forceinline__ void drain(const float* __restrict__ buf, int tblk,
                                      unsigned short* __restrict__ srow, int n0, int l) {
    __builtin_amdgcn_s_barrier();
    asm volatile("" ::: "memory");
    int row8 = l >> 3, cg = l & 7;
#pragma unroll
    for (int i = 0; i < 4; i++) {
        int row = i * 8 + row8;
        float4 a = *reinterpret_cast<const float4*>(&buf[row * SROW + cg * 8]);
        float4 b = *reinterpret_cast<const float4*>(&buf[row * SROW + cg * 8 + 4]);
        uint4 v = { pk2(a.x, a.y), pk2(a.z, a.w), pk2(b.x, b.y), pk2(b.z, b.w) };
        *reinterpret_cast<uint4*>(&srow[((size_t)(tblk + row) << 10) + n0 + cg * 8]) = v;
    }
}

__global__ __launch_bounds__(128) void scan4(const float* __restrict__ xp,
                                             const float* __restrict__ w,
                                             const float* __restrict__ h0,
                                             unsigned short* __restrict__ states,
                                             float* __restrict__ out_state) {
    __shared__ alignas(16) float hb[2][32 * SROW];     // 17 KiB
    const int l = threadIdx.x & 63;
    const int wave = threadIdx.x >> 6;
    const int b = blockIdx.x >> 4;
    const int n0 = (blockIdx.x & 15) * 64;

    if (wave == 0) {
        const int tid = blockIdx.x * 64 + l;           // b*1024 + n
        const int n = tid & (Nc - 1);
        float nw2 = w[n] * (-2.f * K2LE);
        float rr = 0.5f - 0.5f * h0[tid];              // h = 1 - 2*rr
        const float* xrow = xp + ((size_t)b << 22) + n;
        float* hbl0 = &hb[0][l];
        float* hbl1 = &hb[1][l];

        float xa[32], xb[32];
#pragma unroll
        for (int d = 0; d < 32; d++) xa[d] = xrow[(size_t)d << 10];

        int t = 0;
        for (; t + 64 < Sc; t += 64) {
            sblk<true>(xrow, xa, xb, hbl0, t, nw2, rr);
            sblk<true>(xrow, xb, xa, hbl1, t + 32, nw2, rr);
        }
        sblk<true >(xrow, xa, xb, hbl0, t, nw2, rr);
        sblk<false>(xrow, xb, xa, hbl1, t + 32, nw2, rr);
        out_state[tid] = fmaf(-2.f, rr, 1.f);
    } else {
        unsigned short* srow = states + ((size_t)b << 22);
        for (int t = 0; t < Sc; t += 64) {
            drain(hb[0], t, srow, n0, l);
            drain(hb[1], t + 32, srow, n0, l);
        }
    }
}

extern "C" void kernel_launch(void* const* d_in, const int* in_sizes, int n_in,
                              void* d_out, int out_size, void* d_ws, size_t ws_size,
                              hipStream_t stream) {
    const float* x  = (const float*)d_in[0];
    const float* Wi = (const float*)d_in[1];
    const float* bi = (const float*)d_in[2];
    const float* w  = (const float*)d_in[3];
    const float* u  = (const float*)d_in[4];
    const float* Wo = (const float*)d_in[5];
    const float* h0 = (const float*)d_in[6];
    const float* hs = (const float*)d_in[7];
    float* out = (float*)d_out;                          // [M, OUT] fp32
    float* out_state = out + (size_t)Mc * OUTc;          // [B, N] fp32
    float* xp = out;                                     // xp scratch lives in d_out (dead before GEMM2)

    // ws layout (70 MiB): xh 32M | xl 32M | WiTh 2M | WiTl 2M | WoT 2M ; states reuse xh
    char* ws = (char*)d_ws;
    unsigned short* xh   = (unsigned short*)ws;
    unsigned short* xl   = (unsigned short*)(ws + 33554432);
    unsigned short* WiTh = (unsigned short*)(ws + 67108864);
    unsigned short* WiTl = (unsigned short*)(ws + 69206016);
    unsigned short* WoT  = (unsigned short*)(ws + 71303168);
    unsigned short* states = xh;                         // xh dead after gemm3

    split2<<<(Mc * INc / 4 + 255) / 256, 256, 0, stream>>>(x, xh, xl, Mc * INc / 4);
    dim3 tb(32, 8);
    tr_split<true ><<<dim3(Nc / 32, INc / 32), tb, 0, stream>>>(Wi, WiTh, WiTl, INc, Nc);
    tr_split<false><<<dim3(OUTc / 32, Nc / 32), tb, 0, stream>>>(Wo, WoT, nullptr, Nc, OUTc);

    gemm3_bt<<<(Mc / 128) * (Nc / 128), 256, 0, stream>>>(xh, xl, WiTh, WiTl, xp, Nc, INc, bi, u, hs, w);
    scan4<<<64, 128, 0, stream>>>(xp, w, h0, states, out_state);
    gemm_bt<<<(Mc / 128) * (OUTc / 128), 256, 0, stream>>>(states, WoT, out, OUTc, Nc);
}

// Round 5
// 256.943 us; speedup vs baseline: 5.5122x; 1.1288x over previous
//
#include <hip/hip_runtime.h>
#include <hip/hip_bf16.h>

using f16x8 = __attribute__((ext_vector_type(8))) _Float16;
using f32x4 = __attribute__((ext_vector_type(4))) float;

extern "C" __device__ float __ocml_native_exp2_f32(float);

static constexpr int Bc = 4, Sc = 4096, INc = 1024, Nc = 1024, OUTc = 1024;
static constexpr int Mc = Bc * Sc;               // 16384
#define K2LE 2.8853900817779268f                 // 2 * log2(e)

__device__ __forceinline__ unsigned short f2h(float f) {
    return __builtin_bit_cast(unsigned short, (_Float16)f);
}
__device__ __forceinline__ float h2f(unsigned short s) {
    return (float)__builtin_bit_cast(_Float16, s);
}

// ---------------- fp32 -> (f16 hi, f16 lo) split, vectorized ----------------
// x ~ N(0,1): hi residuals (~2e-4) are in f16 normal range -> no denormal hazard.
__global__ __launch_bounds__(256) void split2h(const float* __restrict__ in,
                                               unsigned short* __restrict__ hi,
                                               unsigned short* __restrict__ lo, int n4) {
    int i = blockIdx.x * blockDim.x + threadIdx.x;
    if (i >= n4) return;
    float4 v = reinterpret_cast<const float4*>(in)[i];
    ushort4 h, l;
    h.x = f2h(v.x); l.x = f2h(v.x - h2f(h.x));
    h.y = f2h(v.y); l.y = f2h(v.y - h2f(h.y));
    h.z = f2h(v.z); l.z = f2h(v.z - h2f(h.z));
    h.w = f2h(v.w); l.w = f2h(v.w - h2f(h.w));
    reinterpret_cast<ushort4*>(hi)[i] = h;
    reinterpret_cast<ushort4*>(lo)[i] = l;
}

// ---------------- transpose + f16 convert: out[c][r] = f16(in[r][c]) ----------------
__global__ __launch_bounds__(256) void tr_h(const float* __restrict__ in,
                                            unsigned short* __restrict__ out, int R, int C) {
    __shared__ float t[32][33];
    int c0 = blockIdx.x * 32, r0 = blockIdx.y * 32;
    for (int i = threadIdx.y; i < 32; i += 8)
        t[i][threadIdx.x] = in[(size_t)(r0 + i) * C + c0 + threadIdx.x];
    __syncthreads();
    for (int i = threadIdx.y; i < 32; i += 8)
        out[(size_t)(c0 + i) * R + r0 + threadIdx.x] = f2h(t[threadIdx.x][i]);
}

// ---------------- f16 MFMA GEMM: C[M,N] fp32 = A[M,K] * BT[N,K]^T ----------------
// MODE 0: single-A, no epilogue (GEMM2).
// MODE 1: split-A (Ah+Al), epilogue C = K2LE*(acc + bi + hs*u + w)  (GEMM1).
// Both: XCD-chunked blockIdx swizzle (grid % 8 == 0).
template<int MODE>
__global__ __launch_bounds__(256) void gemm_h(const unsigned short* __restrict__ Ah,
                                              const unsigned short* __restrict__ Al,
                                              const unsigned short* __restrict__ BT,
                                              float* __restrict__ C, int N, int K,
                                              const float* __restrict__ bi,
                                              const float* __restrict__ u,
                                              const float* __restrict__ hs,
                                              const float* __restrict__ wv) {
    constexpr int BM = 128, BN = 128, BK = 64;
    __shared__ alignas(16) unsigned short Ash[BM * BK];
    __shared__ alignas(16) unsigned short Asl[MODE ? BM * BK : 1];
    __shared__ alignas(16) unsigned short Bs[BN * BK];
    const int nb = N >> 7;
    // T1: XCD-chunked swizzle — consecutive logical tiles land on the same XCD L2.
    const int cpx = (int)gridDim.x >> 3;
    const int wg = (blockIdx.x & 7) * cpx + (blockIdx.x >> 3);
    const int bm = wg / nb, bn = wg % nb;
    const int tid = threadIdx.x;
    const int w = tid >> 6, l = tid & 63;
    const int wr = w >> 1, wc = w & 1;
    const int r = l & 15, g4 = l >> 4;
    const int lrow = l >> 3, lcol = (l & 7) * 8;

    f32x4 acc[4][4] = {};

    const size_t aoff = (size_t)bm * BM * K;
    const size_t boff = (size_t)bn * BN * K;

    for (int k0 = 0; k0 < K; k0 += BK) {
        __syncthreads();
#pragma unroll
        for (int i = 0; i < 4; i++) {
            size_t grow = (size_t)((w * 4 + i) * 8 + lrow) * K + (k0 + lcol);
            int ldst = (w * 4 + i) * 512;
            __builtin_amdgcn_global_load_lds(
                (const __attribute__((address_space(1))) void*)(Ah + aoff + grow),
                (__attribute__((address_space(3))) void*)(Ash + ldst), 16, 0, 0);
            if (MODE)
                __builtin_amdgcn_global_load_lds(
                    (const __attribute__((address_space(1))) void*)(Al + aoff + grow),
                    (__attribute__((address_space(3))) void*)(Asl + ldst), 16, 0, 0);
            __builtin_amdgcn_global_load_lds(
                (const __attribute__((address_space(1))) void*)(BT + boff + grow),
                (__attribute__((address_space(3))) void*)(Bs + ldst), 16, 0, 0);
        }
        __syncthreads();
#pragma unroll
        for (int kk = 0; kk < BK; kk += 32) {
            f16x8 ah[4], al[4], bf[4];
#pragma unroll
            for (int m = 0; m < 4; m++) {
                int off = (wr * 64 + m * 16 + r) * BK + kk + g4 * 8;
                ah[m] = *reinterpret_cast<const f16x8*>(Ash + off);
                if (MODE) al[m] = *reinterpret_cast<const f16x8*>(Asl + off);
            }
#pragma unroll
            for (int n = 0; n < 4; n++)
                bf[n] = *reinterpret_cast<const f16x8*>(Bs + (wc * 64 + n * 16 + r) * BK + kk + g4 * 8);
#pragma unroll
            for (int m = 0; m < 4; m++)
#pragma unroll
                for (int n = 0; n < 4; n++) {
                    acc[m][n] = __builtin_amdgcn_mfma_f32_16x16x32_f16(ah[m], bf[n], acc[m][n], 0, 0, 0);
                    if (MODE)
                        acc[m][n] = __builtin_amdgcn_mfma_f32_16x16x32_f16(al[m], bf[n], acc[m][n], 0, 0, 0);
                }
        }
    }

    const int bbase = MODE ? ((bm * BM) / Sc) * Nc : 0;   // batch uniform per block
#pragma unroll
    for (int m = 0; m < 4; m++) {
        int row = bm * BM + wr * 64 + m * 16 + g4 * 4;
#pragma unroll
        for (int n = 0; n < 4; n++) {
            int col = bn * BN + wc * 64 + n * 16 + r;
            float extra = 0.f;
            if (MODE) extra = bi[col] + hs[bbase + col] * u[col] + wv[col];
#pragma unroll
            for (int q = 0; q < 4; q++) {
                float v = acc[m][n][q];
                if (MODE) v = (v + extra) * K2LE;
                C[(size_t)(row + q) * N + col] = v;
            }
        }
    }
}

// ---------------- sequential tanh recurrence: producer-consumer waves ----------------
// xp holds K2LE*(x@Wi + bi + hippo + w). Wave 0 (producer): per step
// z = fma(nw2, rr, x); e = exp2(z); rr = rcp(e+1); ds_write_b32 rr.
// Wave 1 (consumer): per 32-step chunk, reads rr from LDS, h = 1-2rr, packs f16,
// coalesced dwordx4 stores. Double-buffered LDS; raw s_barrier + lgkmcnt-only
// fence on wave 0 so the x-prefetch VMEM queue is NEVER drained.
static constexpr int SROW = 68;   // floats per LDS row (64 + 4 pad, 16B-aligned)

template<bool PREF>
__device__ __forceinline__ void sblk(const float* __restrict__ xrow,
                                     float (&cur)[32], float (&nxt)[32],
                                     float* __restrict__ hbl, int tblk, float nw2, float& rr) {
#pragma unroll
    for (int d = 0; d < 32; d++) {
        if (PREF) nxt[d] = xrow[(size_t)(tblk + 32 + d) << 10];   // 1 chunk ahead
        float z = fmaf(nw2, rr, cur[d]);
        float e = __ocml_native_exp2_f32(z);          // v_exp_f32
        rr = __builtin_amdgcn_rcpf(e + 1.f);          // v_rcp_f32
        hbl[d * SROW] = rr;                            // ds_write_b32, imm offset
    }
    asm volatile("s_waitcnt lgkmcnt(0)" ::: "memory");
    __builtin_amdgcn_s_barrier();
}

__device__ __forceinline__ unsigned int pk2(float a, float b) {
    return ((unsigned int)f2h(fmaf(-2.f, b, 1.f)) << 16) | f2h(fmaf(-2.f, a, 1.f));
}

__device__ __forceinline__ void drain(const float* __restrict__ buf, int tblk,
                                      unsigned short* __restrict__ srow, int n0, int l) {
    __builtin_amdgcn_s_barrier();
    asm volatile("" ::: "memory");
    int row8 = l >> 3, cg = l & 7;
#pragma unroll
    for (int i = 0; i < 4; i++) {
        int row = i * 8 + row8;
        float4 a = *reinterpret_cast<const float4*>(&buf[row * SROW + cg * 8]);
        float4 b = *reinterpret_cast<const float4*>(&buf[row * SROW + cg * 8 + 4]);
        uint4 v = { pk2(a.x, a.y), pk2(a.z, a.w), pk2(b.x, b.y), pk2(b.z, b.w) };
        *reinterpret_cast<uint4*>(&srow[((size_t)(tblk + row) << 10) + n0 + cg * 8]) = v;
    }
}

__global__ __launch_bounds__(128) void scan4(const float* __restrict__ xp,
                                             const float* __restrict__ w,
                                             const float* __restrict__ h0,
                                             unsigned short* __restrict__ states,
                                             float* __restrict__ out_state) {
    __shared__ alignas(16) float hb[2][32 * SROW];     // 17 KiB
    const int l = threadIdx.x & 63;
    const int wave = threadIdx.x >> 6;
    const int b = blockIdx.x >> 4;
    const int n0 = (blockIdx.x & 15) * 64;

    if (wave == 0) {
        const int tid = blockIdx.x * 64 + l;           // b*1024 + n
        const int n = tid & (Nc - 1);
        float nw2 = w[n] * (-2.f * K2LE);
        float rr = 0.5f - 0.5f * h0[tid];              // h = 1 - 2*rr
        const float* xrow = xp + ((size_t)b << 22) + n;
        float* hbl0 = &hb[0][l];
        float* hbl1 = &hb[1][l];

        float xa[32], xb[32];
#pragma unroll
        for (int d = 0; d < 32; d++) xa[d] = xrow[(size_t)d << 10];

        int t = 0;
        for (; t + 64 < Sc; t += 64) {
            sblk<true>(xrow, xa, xb, hbl0, t, nw2, rr);
            sblk<true>(xrow, xb, xa, hbl1, t + 32, nw2, rr);
        }
        sblk<true >(xrow, xa, xb, hbl0, t, nw2, rr);
        sblk<false>(xrow, xb, xa, hbl1, t + 32, nw2, rr);
        out_state[tid] = fmaf(-2.f, rr, 1.f);
    } else {
        unsigned short* srow = states + ((size_t)b << 22);
        for (int t = 0; t < Sc; t += 64) {
            drain(hb[0], t, srow, n0, l);
            drain(hb[1], t + 32, srow, n0, l);
        }
    }
}

extern "C" void kernel_launch(void* const* d_in, const int* in_sizes, int n_in,
                              void* d_out, int out_size, void* d_ws, size_t ws_size,
                              hipStream_t stream) {
    const float* x  = (const float*)d_in[0];
    const float* Wi = (const float*)d_in[1];
    const float* bi = (const float*)d_in[2];
    const float* w  = (const float*)d_in[3];
    const float* u  = (const float*)d_in[4];
    const float* Wo = (const float*)d_in[5];
    const float* h0 = (const float*)d_in[6];
    const float* hs = (const float*)d_in[7];
    float* out = (float*)d_out;                          // [M, OUT] fp32
    float* out_state = out + (size_t)Mc * OUTc;          // [B, N] fp32
    float* xp = out;                                     // xp scratch lives in d_out (dead before GEMM2)

    // ws layout (68 MiB): xh 32M | xl 32M | WiT 2M | WoT 2M ; states (f16) reuse xh
    char* ws = (char*)d_ws;
    unsigned short* xh  = (unsigned short*)ws;
    unsigned short* xl  = (unsigned short*)(ws + 33554432);
    unsigned short* WiT = (unsigned short*)(ws + 67108864);
    unsigned short* WoT = (unsigned short*)(ws + 69206016);
    unsigned short* states = xh;                         // xh dead after gemm1

    split2h<<<(Mc * INc / 4 + 255) / 256, 256, 0, stream>>>(x, xh, xl, Mc * INc / 4);
    dim3 tb(32, 8);
    tr_h<<<dim3(Nc / 32, INc / 32), tb, 0, stream>>>(Wi, WiT, INc, Nc);
    tr_h<<<dim3(OUTc / 32, Nc / 32), tb, 0, stream>>>(Wo, WoT, Nc, OUTc);

    gemm_h<1><<<(Mc / 128) * (Nc / 128), 256, 0, stream>>>(xh, xl, WiT, xp, Nc, INc, bi, u, hs, w);
    scan4<<<64, 128, 0, stream>>>(xp, w, h0, states, out_state);
    gemm_h<0><<<(Mc / 128) * (OUTc / 128), 256, 0, stream>>>(states, nullptr, WoT, out, OUTc, Nc,
                                                             nullptr, nullptr, nullptr, nullptr);
}